// Round 1
// 398.844 us; speedup vs baseline: 1.1548x; 1.1548x over previous
//
#include <hip/hip_runtime.h>

typedef __attribute__((ext_vector_type(8))) short short8;
typedef __attribute__((ext_vector_type(4))) float f32x4;
typedef unsigned short ushort;
typedef unsigned int uint;

#define DIM 1024
#define NSEQ 1024
#define BATCH 8
#define HEADS 16
#define HD 64
#define HIDDEN 4096
#define NROWS (BATCH * NSEQ)  // 8192

__device__ inline ushort f2bf(float f) {
  uint u = __float_as_uint(f);
  u += 0x7fff + ((u >> 16) & 1);  // round-to-nearest-even
  return (ushort)(u >> 16);
}

__device__ inline f32x4 zero4() {
  f32x4 z; z[0] = 0.f; z[1] = 0.f; z[2] = 0.f; z[3] = 0.f; return z;
}

// gelu(x) = x * sigmoid(2u), u = 0.79788456(x + 0.044715 x^3)  (exact identity
// with the tanh form). exp(-2u) = exp2(-2u*log2e).
__device__ inline float gelu_fast(float x) {
  float u2 = 1.5957691216057308f * (x + 0.044715f * x * x * x);  // 2u
  float e = __builtin_amdgcn_exp2f(-1.4426950408889634f * u2);
  return x / (1.0f + e);
}

#define GLDS16(g, l)                                                  \
  __builtin_amdgcn_global_load_lds(                                   \
      (const __attribute__((address_space(1))) void*)(g),             \
      (__attribute__((address_space(3))) void*)(l), 16, 0, 0)

#define WAITVM(n) asm volatile("s_waitcnt vmcnt(" #n ")" ::: "memory")

// ---------------- LayerNorm (fp32 in -> bf16 out) ----------------
__global__ __launch_bounds__(256) void ln_kernel(
    const float* __restrict__ x, const float* __restrict__ sc,
    const float* __restrict__ bi, ushort* __restrict__ out) {
  int row = blockIdx.x;
  int t = threadIdx.x;
  const float4 v = reinterpret_cast<const float4*>(x + (size_t)row * DIM)[t];
  float s = v.x + v.y + v.z + v.w;
  float s2 = v.x * v.x + v.y * v.y + v.z * v.z + v.w * v.w;
#pragma unroll
  for (int off = 32; off >= 1; off >>= 1) {
    s += __shfl_xor(s, off);
    s2 += __shfl_xor(s2, off);
  }
  __shared__ float ps[4], ps2[4];
  int w = t >> 6;
  if ((t & 63) == 0) { ps[w] = s; ps2[w] = s2; }
  __syncthreads();
  s = ps[0] + ps[1] + ps[2] + ps[3];
  s2 = ps2[0] + ps2[1] + ps2[2] + ps2[3];
  float mu = s * (1.0f / DIM);
  float var = s2 * (1.0f / DIM) - mu * mu;
  float rstd = rsqrtf(var + 1e-6f);
  float4 scv = reinterpret_cast<const float4*>(sc)[t];
  float4 biv = reinterpret_cast<const float4*>(bi)[t];
  ushort4 o;
  o.x = f2bf((v.x - mu) * rstd * scv.x + biv.x);
  o.y = f2bf((v.y - mu) * rstd * scv.y + biv.y);
  o.z = f2bf((v.z - mu) * rstd * scv.z + biv.z);
  o.w = f2bf((v.w - mu) * rstd * scv.w + biv.w);
  reinterpret_cast<ushort4*>(out + (size_t)row * DIM)[t] = o;
}

// ---------------- weight transpose fp32 [K][N] -> bf16 [N][K] ----------------
__global__ __launch_bounds__(256) void wtrans_kernel(
    const float* __restrict__ w, ushort* __restrict__ wt, int K, int N) {
  __shared__ float tile[32][33];
  int n0 = blockIdx.x * 32, k0 = blockIdx.y * 32;
  int tx = threadIdx.x & 31, ty = threadIdx.x >> 5;
#pragma unroll
  for (int j = 0; j < 4; j++)
    tile[ty + 8 * j][tx] = w[(size_t)(k0 + ty + 8 * j) * N + n0 + tx];
  __syncthreads();
#pragma unroll
  for (int j = 0; j < 4; j++)
    wt[(size_t)(n0 + ty + 8 * j) * K + k0 + tx] = f2bf(tile[tx][ty + 8 * j]);
}

// ---------------- V transpose: qkv v-part [b,n][h,d] -> vT [b,h,d][n] ----------------
__global__ __launch_bounds__(256) void vtrans_kernel(
    const ushort* __restrict__ qkv, ushort* __restrict__ vT) {
  __shared__ ushort Ts[64 * 64];
  int bh = blockIdx.y;
  int b = bh >> 4, h = bh & 15;
  int n0 = blockIdx.x * 64;
  int t = threadIdx.x;
  const ushort* src = qkv + (size_t)b * NSEQ * 3072 + 2048 + h * 64;
#pragma unroll
  for (int i = 0; i < 2; i++) {
    int ci = i * 256 + t;
    int rr = ci >> 3, c = ci & 7;
    short8 v = *reinterpret_cast<const short8*>(src + (size_t)(n0 + rr) * 3072 + c * 8);
    *reinterpret_cast<short8*>(&Ts[rr * 64 + ((c ^ (rr >> 3)) & 7) * 8]) = v;
  }
  __syncthreads();
  ushort* dst = vT + (size_t)bh * 64 * NSEQ;
#pragma unroll
  for (int i = 0; i < 2; i++) {
    int ci = i * 256 + t;
    int dd = ci >> 3, c = ci & 7;
    short8 v;
#pragma unroll
    for (int j = 0; j < 8; j++) {
      int nn = c * 8 + j;
      v[j] = (short)Ts[nn * 64 + (((dd >> 3) ^ (nn >> 3)) & 7) * 8 + (dd & 7)];
    }
    *reinterpret_cast<short8*>(dst + (size_t)dd * NSEQ + n0 + c * 8) = v;
  }
}

// ---------------- GEMM: phased pipeline, 4-deep LDS circular buffer ----------
// C[M,N] = A[M,K] (bf16) @ Bt[N,K]^T (bf16) + bias.
// EPI: 0 bf16 out, 1 gelu->bf16, 2 +res->fp32.
// Structure (T1+T2+T3+T4+T5 stack):
//  - BK=32, 4 LDS buffers (tile t uses buf t&3); while computing tile t we
//    issue global_load_lds for tile t+3 into buf (t+3)&3 == (t-1)&3, which
//    was fully drained (lgkmcnt(0) + barrier) before tile t began. SAFE.
//  - tile boundary: s_waitcnt vmcnt(2L) (L = loads/thread/tile) -> tiles
//    t+2,t+3 stay IN FLIGHT across the raw s_barrier (no __syncthreads drain).
//  - per phase: {ds_read frags; stage; barrier; lgkmcnt(0); setprio(1);
//    16 MFMA; setprio(0); barrier}.
//  - LDS swizzle: slot (row,c) holds global chunk c ^ (row&3) ^ ((row>>2)&3);
//    each 16-lane group hits every bank-quad exactly 2x (2-way = free).
//  - requires nkt = K/32 >= 3 (K is 1024 or 4096 here).
template <int BN, int EPI>
__global__ __launch_bounds__(512, 2) void gemm256_kernel(
    const ushort* __restrict__ A, const ushort* __restrict__ Bt,
    const float* __restrict__ bias, const float* __restrict__ res,
    void* __restrict__ outp, int M, int N, int K) {
  constexpr int BM = 256, BK = 32;
  constexpr int WM = (BN == 256) ? 2 : 4;  // waves in M
  constexpr int WN = 8 / WM;               // waves in N
  constexpr int MR = (BM / WM) / 16;       // 8 or 4 frags per wave in M
  constexpr int NR = (BN / WN) / 16;       // 4 frags per wave in N
  constexpr int PH = MR / 4;               // 2 or 1 phases per K-tile
  constexpr int AR = 2;                    // A staging rounds (128 rows each)
  constexpr int BR = BN / 128;             // B staging rounds
  static_assert(BN == 256 || BN == 128, "");

  __shared__ ushort As[4][BM * BK];        // 64 KB
  __shared__ ushort Bs[4][BN * BK];        // 64/32 KB

  int t = threadIdx.x, lane = t & 63, w = t >> 6;
  int wr = w / WN, wc = w % WN;
  int r = lane & 15, g = lane >> 4;

  // XCD-aware block swizzle (all grids here are multiples of 8 blocks)
  int nwg = gridDim.x * gridDim.y;
  int flat = blockIdx.y * gridDim.x + blockIdx.x;
  int swzf = (flat & 7) * (nwg >> 3) + (flat >> 3);
  int bx = swzf % gridDim.x, by = swzf / gridDim.x;
  int m0 = by * BM, n0 = bx * BN;

  const ushort* Ab = A + (size_t)m0 * K;
  const ushort* Bb = Bt + (size_t)n0 * K;

  // staging geometry: per round 512 threads cover 128 rows x 4 chunks (16B).
  // LDS dest is linear (wave-uniform base + lane*16B); swizzle applied on the
  // GLOBAL source chunk so slot (row,c) holds chunk c ^ (row&3) ^ ((row>>2)&3).
  int srow = t >> 2;                                            // 0..127
  int sgc8 = (((t & 3) ^ (srow & 3) ^ ((srow >> 2) & 3)) & 3) * 8;
  int swb = (w << 4) * BK;                                      // wave LDS base
  // read-side swizzle: fragment rows are (16*k + r), so swz depends on r only
  int sw = ((g ^ (r & 3) ^ ((r >> 2) & 3)) & 3) * 8;

  auto stageA = [&](int kt2) {
    ushort* as = &As[kt2 & 3][0];
    int ko = kt2 * BK;
#pragma unroll
    for (int p = 0; p < AR; p++)
      GLDS16(Ab + (size_t)(p * 128 + srow) * K + ko + sgc8,
             as + p * 128 * BK + swb);
  };
  auto stageB = [&](int kt2) {
    ushort* bs = &Bs[kt2 & 3][0];
    int ko = kt2 * BK;
#pragma unroll
    for (int p = 0; p < BR; p++)
      GLDS16(Bb + (size_t)(p * 128 + srow) * K + ko + sgc8,
             bs + p * 128 * BK + swb);
  };

  f32x4 acc[MR][NR];
#pragma unroll
  for (int mi = 0; mi < MR; mi++)
#pragma unroll
    for (int ni = 0; ni < NR; ni++) acc[mi][ni] = zero4();

  int nkt = K / BK;  // >= 3 required

  // prologue: stage tiles 0,1,2; wait for tile 0 only (tiles 1,2 in flight)
  stageA(0); stageB(0);
  stageA(1); stageB(1);
  stageA(2); stageB(2);
  if constexpr (BN == 256) WAITVM(8); else WAITVM(6);
  __builtin_amdgcn_s_barrier();
  asm volatile("" ::: "memory");

  for (int kt = 0; kt < nkt; kt++) {
    const ushort* as = &As[kt & 3][0];
    const ushort* bs = &Bs[kt & 3][0];
    short8 b[NR];
#pragma unroll
    for (int ph = 0; ph < PH; ph++) {
      // ---- issue slots: ds_read this phase's fragments + stage tile kt+3 ----
      if (ph == 0) {
#pragma unroll
        for (int ni = 0; ni < NR; ni++)
          b[ni] = *reinterpret_cast<const short8*>(
              &bs[(wc * (BN / WN) + ni * 16 + r) * BK + sw]);
      }
      short8 a[4];
#pragma unroll
      for (int i = 0; i < 4; i++)
        a[i] = *reinterpret_cast<const short8*>(
            &as[(wr * (BM / WM) + (ph * 4 + i) * 16 + r) * BK + sw]);
      if (kt + 3 < nkt) {
        if constexpr (PH == 2) {
          if (ph == 0) stageA(kt + 3); else stageB(kt + 3);
        } else {
          stageA(kt + 3); stageB(kt + 3);
        }
      }
      // ---- tile boundary: counted vmcnt AFTER all of tile kt+3 issued ----
      if (ph == PH - 1) {
        if (kt + 3 < nkt) {
          if constexpr (BN == 256) WAITVM(8); else WAITVM(6);   // t+1 done
        } else if (kt + 2 < nkt) {
          if constexpr (BN == 256) WAITVM(4); else WAITVM(3);   // tail
        } else if (kt + 1 < nkt) {
          WAITVM(0);                                            // tail
        }
      }
      __builtin_amdgcn_s_barrier();
      asm volatile("s_waitcnt lgkmcnt(0)" ::: "memory");
      __builtin_amdgcn_sched_barrier(0);
      __builtin_amdgcn_s_setprio(1);
#pragma unroll
      for (int i = 0; i < 4; i++)
#pragma unroll
        for (int ni = 0; ni < NR; ni++)
          acc[ph * 4 + i][ni] = __builtin_amdgcn_mfma_f32_16x16x32_bf16(
              a[i], b[ni], acc[ph * 4 + i][ni], 0, 0, 0);
      __builtin_amdgcn_s_setprio(0);
      __builtin_amdgcn_s_barrier();
      asm volatile("" ::: "memory");
    }
  }

  int rg = g * 4;
#pragma unroll
  for (int mi = 0; mi < MR; mi++) {
#pragma unroll
    for (int ni = 0; ni < NR; ni++) {
      int row = m0 + wr * (BM / WM) + mi * 16 + rg;
      int col = n0 + wc * (BN / WN) + ni * 16 + r;
      float bv = bias[col];
#pragma unroll
      for (int j = 0; j < 4; j++) {
        float v = acc[mi][ni][j] + bv;
        if (EPI == 1) v = gelu_fast(v);
        if (EPI == 2) {
          reinterpret_cast<float*>(outp)[(size_t)(row + j) * N + col] =
              v + res[(size_t)(row + j) * N + col];
        } else {
          reinterpret_cast<ushort*>(outp)[(size_t)(row + j) * N + col] = f2bf(v);
        }
      }
    }
  }
}

// ---------------- flash attention (no-max-subtract softmax) ----------------
#define SM_SCALE_L2E 0.18033688f   // 0.125 * log2(e)
#define SM_BIAS_L2E 11.54156036f   // 8 * log2(e)
__global__ __launch_bounds__(256) void attn_kernel(
    const ushort* __restrict__ qkv, const ushort* __restrict__ vT,
    ushort* __restrict__ o) {
  __shared__ ushort Kt[64 * 72];
  __shared__ ushort Vt[64 * 72];
  __shared__ ushort Pl[4][16 * 72];
  int q0 = blockIdx.x * 64, h = blockIdx.y, b = blockIdx.z;
  int t = threadIdx.x, lane = t & 63, w = t >> 6;
  int r = lane & 15, g = lane >> 4;
  const ushort* base = qkv + (size_t)b * NSEQ * 3072 + h * 64;
  const ushort* vbase = vT + (size_t)(b * HEADS + h) * 64 * NSEQ;

  short8 qf[2];
  {
    const ushort* qrow = base + (size_t)(q0 + w * 16 + r) * 3072;
    qf[0] = *reinterpret_cast<const short8*>(qrow + g * 8);
    qf[1] = *reinterpret_cast<const short8*>(qrow + 32 + g * 8);
  }

  float l[4] = {0.f, 0.f, 0.f, 0.f};
  f32x4 oacc[4];
#pragma unroll
  for (int db = 0; db < 4; db++) oacc[db] = zero4();

  int srw = t >> 3, sc8 = (t & 7) * 8;
  for (int kt = 0; kt < NSEQ / 64; kt++) {
    int k0 = kt * 64;
    short8 kreg[2], vreg[2];
#pragma unroll
    for (int i = 0; i < 2; i++) {
      int rw = srw + i * 32;
      kreg[i] = *reinterpret_cast<const short8*>(base + 1024 + (size_t)(k0 + rw) * 3072 + sc8);
      vreg[i] = *reinterpret_cast<const short8*>(vbase + (size_t)rw * NSEQ + k0 + sc8);
    }
    __syncthreads();
#pragma unroll
    for (int i = 0; i < 2; i++) {
      int rw = srw + i * 32;
      *reinterpret_cast<short8*>(&Kt[rw * 72 + sc8]) = kreg[i];
      *reinterpret_cast<short8*>(&Vt[rw * 72 + sc8]) = vreg[i];
    }
    __syncthreads();

#pragma unroll
    for (int kb = 0; kb < 4; kb++) {
      short8 kf0 = *reinterpret_cast<const short8*>(&Kt[(kb * 16 + r) * 72 + g * 8]);
      short8 kf1 = *reinterpret_cast<const short8*>(&Kt[(kb * 16 + r) * 72 + 32 + g * 8]);
      f32x4 z = zero4();
      z = __builtin_amdgcn_mfma_f32_16x16x32_bf16(qf[0], kf0, z, 0, 0, 0);
      z = __builtin_amdgcn_mfma_f32_16x16x32_bf16(qf[1], kf1, z, 0, 0, 0);
#pragma unroll
      for (int j = 0; j < 4; j++) {
        float p = __builtin_amdgcn_exp2f(fmaf(z[j], SM_SCALE_L2E, -SM_BIAS_L2E));
        l[j] += p;
        Pl[w][(g * 4 + j) * 72 + kb * 16 + r] = (ushort)(__float_as_uint(p) >> 16);
      }
    }

#pragma unroll
    for (int ks = 0; ks < 2; ks++) {
      short8 pa = *reinterpret_cast<const short8*>(&Pl[w][r * 72 + ks * 32 + g * 8]);
#pragma unroll
      for (int db = 0; db < 4; db++) {
        short8 vb = *reinterpret_cast<const short8*>(&Vt[(db * 16 + r) * 72 + ks * 32 + g * 8]);
        oacc[db] = __builtin_amdgcn_mfma_f32_16x16x32_bf16(pa, vb, oacc[db], 0, 0, 0);
      }
    }
  }

#pragma unroll
  for (int j = 0; j < 4; j++) {
#pragma unroll
    for (int off = 8; off >= 1; off >>= 1) l[j] += __shfl_xor(l[j], off);
    l[j] = 1.0f / l[j];
  }

#pragma unroll
  for (int db = 0; db < 4; db++)
#pragma unroll
    for (int j = 0; j < 4; j++) {
      size_t row = (size_t)b * NSEQ + q0 + w * 16 + g * 4 + j;
      int col = h * 64 + db * 16 + r;
      o[row * DIM + col] = f2bf(oacc[db][j] * l[j]);
    }
}

// ---------------- driver ----------------
extern "C" void kernel_launch(void* const* d_in, const int* in_sizes, int n_in,
                              void* d_out, int out_size, void* d_ws, size_t ws_size,
                              hipStream_t stream) {
  const float* x      = (const float*)d_in[0];
  const float* w_qkv  = (const float*)d_in[1];
  const float* b_qkv  = (const float*)d_in[2];
  const float* w_proj = (const float*)d_in[3];
  const float* b_proj = (const float*)d_in[4];
  const float* ln1s   = (const float*)d_in[5];
  const float* ln1b   = (const float*)d_in[6];
  const float* ln2s   = (const float*)d_in[7];
  const float* ln2b   = (const float*)d_in[8];
  const float* w_fc1  = (const float*)d_in[9];
  const float* b_fc1  = (const float*)d_in[10];
  const float* w_fc2  = (const float*)d_in[11];
  const float* b_fc2  = (const float*)d_in[12];
  float* out = (float*)d_out;

  char* ws = (char*)d_ws;
  ushort* wqkv_t  = (ushort*)(ws);               // [3072][1024] bf16, 6 MB
  ushort* wproj_t = (ushort*)(ws + 6291456);     // [1024][1024], 2 MB
  ushort* wfc1_t  = (ushort*)(ws + 8388608);     // [4096][1024], 8 MB
  ushort* wfc2_t  = (ushort*)(ws + 16777216);    // [1024][4096], 8 MB
  ushort* hbuf    = (ushort*)(ws + 25165824);    // [8192][1024] bf16, 16 MB
  float*  x1      = (float*)(ws + 41943040);     // [8192][1024] f32, 32 MB
  ushort* vTb     = (ushort*)(ws + 41943040);    // [128][64][1024] bf16, 16 MB (dead before x1)
  ushort* qkv     = (ushort*)(ws + 75497472);    // [8192][3072] bf16, 48 MB
  ushort* obuf    = (ushort*)(ws + 125829120);   // [8192][1024] bf16, 16 MB
  ushort* fc1a    = qkv;                         // [8192][4096] bf16, 64 MB

  wtrans_kernel<<<dim3(3072 / 32, 1024 / 32), 256, 0, stream>>>(w_qkv, wqkv_t, 1024, 3072);
  wtrans_kernel<<<dim3(1024 / 32, 1024 / 32), 256, 0, stream>>>(w_proj, wproj_t, 1024, 1024);
  wtrans_kernel<<<dim3(4096 / 32, 1024 / 32), 256, 0, stream>>>(w_fc1, wfc1_t, 1024, 4096);
  wtrans_kernel<<<dim3(1024 / 32, 4096 / 32), 256, 0, stream>>>(w_fc2, wfc2_t, 4096, 1024);

  // attention branch
  ln_kernel<<<NROWS, 256, 0, stream>>>(x, ln1s, ln1b, hbuf);
  gemm256_kernel<128, 0><<<dim3(3072 / 128, NROWS / 256), 512, 0, stream>>>(
      hbuf, wqkv_t, b_qkv, nullptr, qkv, NROWS, 3072, 1024);
  vtrans_kernel<<<dim3(NSEQ / 64, BATCH * HEADS), 256, 0, stream>>>(qkv, vTb);
  attn_kernel<<<dim3(NSEQ / 64, HEADS, BATCH), 256, 0, stream>>>(qkv, vTb, obuf);
  gemm256_kernel<128, 2><<<dim3(1024 / 128, NROWS / 256), 512, 0, stream>>>(
      obuf, wproj_t, b_proj, x, x1, NROWS, 1024, 1024);

  // mlp branch
  ln_kernel<<<NROWS, 256, 0, stream>>>(x1, ln2s, ln2b, hbuf);
  gemm256_kernel<256, 1><<<dim3(4096 / 256, NROWS / 256), 512, 0, stream>>>(
      hbuf, wfc1_t, b_fc1, nullptr, fc1a, NROWS, 4096, 1024);
  gemm256_kernel<128, 2><<<dim3(1024 / 128, NROWS / 256), 512, 0, stream>>>(
      fc1a, wfc2_t, b_fc2, x1, out, NROWS, 1024, 4096);
}

// Round 2
// 389.729 us; speedup vs baseline: 1.1818x; 1.0234x over previous
//
#include <hip/hip_runtime.h>

typedef __attribute__((ext_vector_type(8))) short short8;
typedef __attribute__((ext_vector_type(4))) float f32x4;
typedef unsigned short ushort;
typedef unsigned int uint;

#define DIM 1024
#define NSEQ 1024
#define BATCH 8
#define HEADS 16
#define HD 64
#define HIDDEN 4096
#define NROWS (BATCH * NSEQ)  // 8192

__device__ inline ushort f2bf(float f) {
  uint u = __float_as_uint(f);
  u += 0x7fff + ((u >> 16) & 1);  // round-to-nearest-even
  return (ushort)(u >> 16);
}

__device__ inline f32x4 zero4() {
  f32x4 z; z[0] = 0.f; z[1] = 0.f; z[2] = 0.f; z[3] = 0.f; return z;
}

// gelu(x) = x * sigmoid(2u), u = 0.79788456(x + 0.044715 x^3)  (exact identity
// with the tanh form). exp(-2u) = exp2(-2u*log2e).
__device__ inline float gelu_fast(float x) {
  float u2 = 1.5957691216057308f * (x + 0.044715f * x * x * x);  // 2u
  float e = __builtin_amdgcn_exp2f(-1.4426950408889634f * u2);
  return x / (1.0f + e);
}

#define GLDS16(g, l)                                                  \
  __builtin_amdgcn_global_load_lds(                                   \
      (const __attribute__((address_space(1))) void*)(g),             \
      (__attribute__((address_space(3))) void*)(l), 16, 0, 0)

#define WAITVM(n) asm volatile("s_waitcnt vmcnt(" #n ")" ::: "memory")
#define SBAR() asm volatile("s_barrier" ::: "memory")

// ---------------- LayerNorm (fp32 in -> bf16 out) ----------------
__global__ __launch_bounds__(256) void ln_kernel(
    const float* __restrict__ x, const float* __restrict__ sc,
    const float* __restrict__ bi, ushort* __restrict__ out) {
  int row = blockIdx.x;
  int t = threadIdx.x;
  const float4 v = reinterpret_cast<const float4*>(x + (size_t)row * DIM)[t];
  float s = v.x + v.y + v.z + v.w;
  float s2 = v.x * v.x + v.y * v.y + v.z * v.z + v.w * v.w;
#pragma unroll
  for (int off = 32; off >= 1; off >>= 1) {
    s += __shfl_xor(s, off);
    s2 += __shfl_xor(s2, off);
  }
  __shared__ float ps[4], ps2[4];
  int w = t >> 6;
  if ((t & 63) == 0) { ps[w] = s; ps2[w] = s2; }
  __syncthreads();
  s = ps[0] + ps[1] + ps[2] + ps[3];
  s2 = ps2[0] + ps2[1] + ps2[2] + ps2[3];
  float mu = s * (1.0f / DIM);
  float var = s2 * (1.0f / DIM) - mu * mu;
  float rstd = rsqrtf(var + 1e-6f);
  float4 scv = reinterpret_cast<const float4*>(sc)[t];
  float4 biv = reinterpret_cast<const float4*>(bi)[t];
  ushort4 o;
  o.x = f2bf((v.x - mu) * rstd * scv.x + biv.x);
  o.y = f2bf((v.y - mu) * rstd * scv.y + biv.y);
  o.z = f2bf((v.z - mu) * rstd * scv.z + biv.z);
  o.w = f2bf((v.w - mu) * rstd * scv.w + biv.w);
  reinterpret_cast<ushort4*>(out + (size_t)row * DIM)[t] = o;
}

// ---------------- weight transpose fp32 [K][N] -> bf16 [N][K] ----------------
__global__ __launch_bounds__(256) void wtrans_kernel(
    const float* __restrict__ w, ushort* __restrict__ wt, int K, int N) {
  __shared__ float tile[32][33];
  int n0 = blockIdx.x * 32, k0 = blockIdx.y * 32;
  int tx = threadIdx.x & 31, ty = threadIdx.x >> 5;
#pragma unroll
  for (int j = 0; j < 4; j++)
    tile[ty + 8 * j][tx] = w[(size_t)(k0 + ty + 8 * j) * N + n0 + tx];
  __syncthreads();
#pragma unroll
  for (int j = 0; j < 4; j++)
    wt[(size_t)(n0 + ty + 8 * j) * K + k0 + tx] = f2bf(tile[tx][ty + 8 * j]);
}

// ---------------- V transpose: qkv v-part [b,n][h,d] -> vT [b,h,d][n] ----------------
__global__ __launch_bounds__(256) void vtrans_kernel(
    const ushort* __restrict__ qkv, ushort* __restrict__ vT) {
  __shared__ ushort Ts[64 * 64];
  int bh = blockIdx.y;
  int b = bh >> 4, h = bh & 15;
  int n0 = blockIdx.x * 64;
  int t = threadIdx.x;
  const ushort* src = qkv + (size_t)b * NSEQ * 3072 + 2048 + h * 64;
#pragma unroll
  for (int i = 0; i < 2; i++) {
    int ci = i * 256 + t;
    int rr = ci >> 3, c = ci & 7;
    short8 v = *reinterpret_cast<const short8*>(src + (size_t)(n0 + rr) * 3072 + c * 8);
    *reinterpret_cast<short8*>(&Ts[rr * 64 + ((c ^ (rr >> 3)) & 7) * 8]) = v;
  }
  __syncthreads();
  ushort* dst = vT + (size_t)bh * 64 * NSEQ;
#pragma unroll
  for (int i = 0; i < 2; i++) {
    int ci = i * 256 + t;
    int dd = ci >> 3, c = ci & 7;
    short8 v;
#pragma unroll
    for (int j = 0; j < 8; j++) {
      int nn = c * 8 + j;
      v[j] = (short)Ts[nn * 64 + (((dd >> 3) ^ (nn >> 3)) & 7) * 8 + (dd & 7)];
    }
    *reinterpret_cast<short8*>(dst + (size_t)dd * NSEQ + n0 + c * 8) = v;
  }
}

// ---------------- GEMM: 1 barrier/K-tile, register prefetch 1 tile ahead ----
// C[M,N] = A[M,K] (bf16) @ Bt[N,K]^T (bf16) + bias.
// EPI: 0 bf16 out, 1 gelu->bf16, 2 +res->fp32.  KK: compile-time K.
// Structure:
//  - 4-deep LDS circular buffer, BK=32; stage(kt+3) issued during tile kt.
//  - fragment regs double-buffered: ds_reads for tile kt+1 issued BEFORE
//    MFMAs of tile kt -> LDS port time overlaps MFMA pipe time (they were
//    ADDING under the old 2-barriers-per-phase schedule: MfmaUtil 21%).
//  - ONE vmcnt(L)+s_barrier per K-tile (L = loads/thread/tile): at end of
//    body(kt) wait stage(kt+2) done (leaves stage(kt+3) in flight), barrier.
//    Safety: reads of buf[kt-1] completed before each wave's MFMA(kt-1)
//    (compiler lgkm) which precedes the end-of-(kt-1) barrier, so
//    stage(kt+3)->buf[kt-1] issued after that barrier cannot race.
//  - two-copy unrolled loop body keeps fragment indices static (no scratch).
template <int BN, int EPI, int KK>
__global__ __launch_bounds__(512, 2) void gemm256_kernel(
    const ushort* __restrict__ A, const ushort* __restrict__ Bt,
    const float* __restrict__ bias, const float* __restrict__ res,
    void* __restrict__ outp, int M, int N) {
  constexpr int BM = 256, BK = 32;
  constexpr int WM = (BN == 256) ? 2 : 4;  // waves in M
  constexpr int WN = 8 / WM;               // waves in N
  constexpr int MR = (BM / WM) / 16;       // 8 or 4 frags per wave in M
  constexpr int NR = (BN / WN) / 16;       // 4 frags per wave in N
  constexpr int AR = 2;                    // A staging rounds (128 rows each)
  constexpr int BR = BN / 128;             // B staging rounds
  constexpr int nkt = KK / BK;             // 32 or 128 (even)
  static_assert(BN == 256 || BN == 128, "");
  static_assert(nkt >= 4 && (nkt % 2) == 0, "");

  __shared__ ushort As[4][BM * BK];        // 64 KB
  __shared__ ushort Bs[4][BN * BK];        // 64/32 KB

  int t = threadIdx.x, lane = t & 63, w = t >> 6;
  int wr = w / WN, wc = w % WN;
  int r = lane & 15, g = lane >> 4;

  // XCD-aware block swizzle (all grids here are multiples of 8 blocks)
  int nwg = gridDim.x * gridDim.y;
  int flat = blockIdx.y * gridDim.x + blockIdx.x;
  int swzf = (flat & 7) * (nwg >> 3) + (flat >> 3);
  int bx = swzf % gridDim.x, by = swzf / gridDim.x;
  int m0 = by * BM, n0 = bx * BN;

  const ushort* Ab = A + (size_t)m0 * KK;
  const ushort* Bb = Bt + (size_t)n0 * KK;

  // staging geometry: per round 512 threads cover 128 rows x 4 chunks (16B).
  // LDS dest linear (gload_lds: base + lane*16B); swizzle on the GLOBAL chunk
  // so LDS slot (row,c) holds global chunk c ^ (row&3) ^ ((row>>2)&3).
  int srow = t >> 2;                                            // 0..127
  int sgc8 = (((t & 3) ^ (srow & 3) ^ ((srow >> 2) & 3)) & 3) * 8;
  int swb = (w << 4) * BK;                                      // wave LDS base
  int sw = ((g ^ (r & 3) ^ ((r >> 2) & 3)) & 3) * 8;            // read swizzle

  auto stageAB = [&](int kt2) {
    ushort* as = &As[kt2 & 3][0];
    ushort* bs = &Bs[kt2 & 3][0];
    int ko = kt2 * BK;
#pragma unroll
    for (int p = 0; p < AR; p++)
      GLDS16(Ab + (size_t)(p * 128 + srow) * KK + ko + sgc8,
             as + p * 128 * BK + swb);
#pragma unroll
    for (int p = 0; p < BR; p++)
      GLDS16(Bb + (size_t)(p * 128 + srow) * KK + ko + sgc8,
             bs + p * 128 * BK + swb);
  };

  auto ldfrags = [&](int kt2, short8 (&fa_)[MR], short8 (&fb_)[NR]) {
    const ushort* as = &As[kt2 & 3][0];
    const ushort* bs = &Bs[kt2 & 3][0];
#pragma unroll
    for (int mi = 0; mi < MR; mi++)
      fa_[mi] = *reinterpret_cast<const short8*>(
          &as[(wr * (BM / WM) + mi * 16 + r) * BK + sw]);
#pragma unroll
    for (int ni = 0; ni < NR; ni++)
      fb_[ni] = *reinterpret_cast<const short8*>(
          &bs[(wc * (BN / WN) + ni * 16 + r) * BK + sw]);
  };

  f32x4 acc[MR][NR];
#pragma unroll
  for (int mi = 0; mi < MR; mi++)
#pragma unroll
    for (int ni = 0; ni < NR; ni++) acc[mi][ni] = zero4();

  auto body = [&](int kt, short8 (&ca)[MR], short8 (&cb)[NR],
                  short8 (&na)[MR], short8 (&nb)[NR]) {
    if (kt + 1 < nkt) ldfrags(kt + 1, na, nb);   // overlaps MFMAs below
    if (kt + 3 < nkt) stageAB(kt + 3);           // HBM -> buf[kt-1]
    __builtin_amdgcn_s_setprio(1);
#pragma unroll
    for (int mi = 0; mi < MR; mi++)
#pragma unroll
      for (int ni = 0; ni < NR; ni++)
        acc[mi][ni] = __builtin_amdgcn_mfma_f32_16x16x32_bf16(
            ca[mi], cb[ni], acc[mi][ni], 0, 0, 0);
    __builtin_amdgcn_s_setprio(0);
    if (kt + 3 < nkt) {
      // stage(kt+2) done for next body's reads; stage(kt+3) stays in flight
      if constexpr (BN == 256) WAITVM(4); else WAITVM(3);
      SBAR();
    } else if (kt + 2 < nkt) {
      WAITVM(0);
      SBAR();
    }  // else: last-2 tiles, no future reads/stages -> no sync needed
  };

  // prologue: 3 tiles in flight; wait stage(0),(1) done (stage(2) in flight)
  stageAB(0); stageAB(1); stageAB(2);
  if constexpr (BN == 256) WAITVM(4); else WAITVM(3);
  SBAR();

  short8 fa[2][MR], fb[2][NR];
  ldfrags(0, fa[0], fb[0]);
#pragma unroll 1
  for (int k2 = 0; k2 < nkt / 2; k2++) {
    body(2 * k2 + 0, fa[0], fb[0], fa[1], fb[1]);
    body(2 * k2 + 1, fa[1], fb[1], fa[0], fb[0]);
  }

  int rg = g * 4;
#pragma unroll
  for (int mi = 0; mi < MR; mi++) {
#pragma unroll
    for (int ni = 0; ni < NR; ni++) {
      int row = m0 + wr * (BM / WM) + mi * 16 + rg;
      int col = n0 + wc * (BN / WN) + ni * 16 + r;
      float bv = bias[col];
#pragma unroll
      for (int j = 0; j < 4; j++) {
        float v = acc[mi][ni][j] + bv;
        if (EPI == 1) v = gelu_fast(v);
        if (EPI == 2) {
          reinterpret_cast<float*>(outp)[(size_t)(row + j) * N + col] =
              v + res[(size_t)(row + j) * N + col];
        } else {
          reinterpret_cast<ushort*>(outp)[(size_t)(row + j) * N + col] = f2bf(v);
        }
      }
    }
  }
}

// ---------------- flash attention (no-max-subtract softmax) ----------------
#define SM_SCALE_L2E 0.18033688f   // 0.125 * log2(e)
#define SM_BIAS_L2E 11.54156036f   // 8 * log2(e)
__global__ __launch_bounds__(256) void attn_kernel(
    const ushort* __restrict__ qkv, const ushort* __restrict__ vT,
    ushort* __restrict__ o) {
  __shared__ ushort Kt[64 * 72];
  __shared__ ushort Vt[64 * 72];
  __shared__ ushort Pl[4][16 * 72];
  int q0 = blockIdx.x * 64, h = blockIdx.y, b = blockIdx.z;
  int t = threadIdx.x, lane = t & 63, w = t >> 6;
  int r = lane & 15, g = lane >> 4;
  const ushort* base = qkv + (size_t)b * NSEQ * 3072 + h * 64;
  const ushort* vbase = vT + (size_t)(b * HEADS + h) * 64 * NSEQ;

  short8 qf[2];
  {
    const ushort* qrow = base + (size_t)(q0 + w * 16 + r) * 3072;
    qf[0] = *reinterpret_cast<const short8*>(qrow + g * 8);
    qf[1] = *reinterpret_cast<const short8*>(qrow + 32 + g * 8);
  }

  float l[4] = {0.f, 0.f, 0.f, 0.f};
  f32x4 oacc[4];
#pragma unroll
  for (int db = 0; db < 4; db++) oacc[db] = zero4();

  int srw = t >> 3, sc8 = (t & 7) * 8;
  for (int kt = 0; kt < NSEQ / 64; kt++) {
    int k0 = kt * 64;
    short8 kreg[2], vreg[2];
#pragma unroll
    for (int i = 0; i < 2; i++) {
      int rw = srw + i * 32;
      kreg[i] = *reinterpret_cast<const short8*>(base + 1024 + (size_t)(k0 + rw) * 3072 + sc8);
      vreg[i] = *reinterpret_cast<const short8*>(vbase + (size_t)rw * NSEQ + k0 + sc8);
    }
    __syncthreads();
#pragma unroll
    for (int i = 0; i < 2; i++) {
      int rw = srw + i * 32;
      *reinterpret_cast<short8*>(&Kt[rw * 72 + sc8]) = kreg[i];
      *reinterpret_cast<short8*>(&Vt[rw * 72 + sc8]) = vreg[i];
    }
    __syncthreads();

#pragma unroll
    for (int kb = 0; kb < 4; kb++) {
      short8 kf0 = *reinterpret_cast<const short8*>(&Kt[(kb * 16 + r) * 72 + g * 8]);
      short8 kf1 = *reinterpret_cast<const short8*>(&Kt[(kb * 16 + r) * 72 + 32 + g * 8]);
      f32x4 z = zero4();
      z = __builtin_amdgcn_mfma_f32_16x16x32_bf16(qf[0], kf0, z, 0, 0, 0);
      z = __builtin_amdgcn_mfma_f32_16x16x32_bf16(qf[1], kf1, z, 0, 0, 0);
#pragma unroll
      for (int j = 0; j < 4; j++) {
        float p = __builtin_amdgcn_exp2f(fmaf(z[j], SM_SCALE_L2E, -SM_BIAS_L2E));
        l[j] += p;
        Pl[w][(g * 4 + j) * 72 + kb * 16 + r] = (ushort)(__float_as_uint(p) >> 16);
      }
    }

#pragma unroll
    for (int ks = 0; ks < 2; ks++) {
      short8 pa = *reinterpret_cast<const short8*>(&Pl[w][r * 72 + ks * 32 + g * 8]);
#pragma unroll
      for (int db = 0; db < 4; db++) {
        short8 vb = *reinterpret_cast<const short8*>(&Vt[(db * 16 + r) * 72 + ks * 32 + g * 8]);
        oacc[db] = __builtin_amdgcn_mfma_f32_16x16x32_bf16(pa, vb, oacc[db], 0, 0, 0);
      }
    }
  }

#pragma unroll
  for (int j = 0; j < 4; j++) {
#pragma unroll
    for (int off = 8; off >= 1; off >>= 1) l[j] += __shfl_xor(l[j], off);
    l[j] = 1.0f / l[j];
  }

#pragma unroll
  for (int db = 0; db < 4; db++)
#pragma unroll
    for (int j = 0; j < 4; j++) {
      size_t row = (size_t)b * NSEQ + q0 + w * 16 + g * 4 + j;
      int col = h * 64 + db * 16 + r;
      o[row * DIM + col] = f2bf(oacc[db][j] * l[j]);
    }
}

// ---------------- driver ----------------
extern "C" void kernel_launch(void* const* d_in, const int* in_sizes, int n_in,
                              void* d_out, int out_size, void* d_ws, size_t ws_size,
                              hipStream_t stream) {
  const float* x      = (const float*)d_in[0];
  const float* w_qkv  = (const float*)d_in[1];
  const float* b_qkv  = (const float*)d_in[2];
  const float* w_proj = (const float*)d_in[3];
  const float* b_proj = (const float*)d_in[4];
  const float* ln1s   = (const float*)d_in[5];
  const float* ln1b   = (const float*)d_in[6];
  const float* ln2s   = (const float*)d_in[7];
  const float* ln2b   = (const float*)d_in[8];
  const float* w_fc1  = (const float*)d_in[9];
  const float* b_fc1  = (const float*)d_in[10];
  const float* w_fc2  = (const float*)d_in[11];
  const float* b_fc2  = (const float*)d_in[12];
  float* out = (float*)d_out;

  char* ws = (char*)d_ws;
  ushort* wqkv_t  = (ushort*)(ws);               // [3072][1024] bf16, 6 MB
  ushort* wproj_t = (ushort*)(ws + 6291456);     // [1024][1024], 2 MB
  ushort* wfc1_t  = (ushort*)(ws + 8388608);     // [4096][1024], 8 MB
  ushort* wfc2_t  = (ushort*)(ws + 16777216);    // [1024][4096], 8 MB
  ushort* hbuf    = (ushort*)(ws + 25165824);    // [8192][1024] bf16, 16 MB
  float*  x1      = (float*)(ws + 41943040);     // [8192][1024] f32, 32 MB
  ushort* vTb     = (ushort*)(ws + 41943040);    // [128][64][1024] bf16, 16 MB (dead before x1)
  ushort* qkv     = (ushort*)(ws + 75497472);    // [8192][3072] bf16, 48 MB
  ushort* obuf    = (ushort*)(ws + 125829120);   // [8192][1024] bf16, 16 MB
  ushort* fc1a    = qkv;                         // [8192][4096] bf16, 64 MB

  wtrans_kernel<<<dim3(3072 / 32, 1024 / 32), 256, 0, stream>>>(w_qkv, wqkv_t, 1024, 3072);
  wtrans_kernel<<<dim3(1024 / 32, 1024 / 32), 256, 0, stream>>>(w_proj, wproj_t, 1024, 1024);
  wtrans_kernel<<<dim3(4096 / 32, 1024 / 32), 256, 0, stream>>>(w_fc1, wfc1_t, 1024, 4096);
  wtrans_kernel<<<dim3(1024 / 32, 4096 / 32), 256, 0, stream>>>(w_fc2, wfc2_t, 4096, 1024);

  // attention branch
  ln_kernel<<<NROWS, 256, 0, stream>>>(x, ln1s, ln1b, hbuf);
  gemm256_kernel<128, 0, 1024><<<dim3(3072 / 128, NROWS / 256), 512, 0, stream>>>(
      hbuf, wqkv_t, b_qkv, nullptr, qkv, NROWS, 3072);
  vtrans_kernel<<<dim3(NSEQ / 64, BATCH * HEADS), 256, 0, stream>>>(qkv, vTb);
  attn_kernel<<<dim3(NSEQ / 64, HEADS, BATCH), 256, 0, stream>>>(qkv, vTb, obuf);
  gemm256_kernel<128, 2, 1024><<<dim3(1024 / 128, NROWS / 256), 512, 0, stream>>>(
      obuf, wproj_t, b_proj, x, x1, NROWS, 1024);

  // mlp branch
  ln_kernel<<<NROWS, 256, 0, stream>>>(x1, ln2s, ln2b, hbuf);
  gemm256_kernel<256, 1, 1024><<<dim3(4096 / 256, NROWS / 256), 512, 0, stream>>>(
      hbuf, wfc1_t, b_fc1, nullptr, fc1a, NROWS, 4096);
  gemm256_kernel<128, 2, 4096><<<dim3(1024 / 128, NROWS / 256), 512, 0, stream>>>(
      fc1a, wfc2_t, b_fc2, x1, out, NROWS, 1024);
}